// Round 2
// 824.119 us; speedup vs baseline: 1.1868x; 1.1868x over previous
//
#include <hip/hip_runtime.h>
#include <hip/hip_bf16.h>
#include <stdint.h>

// E=1e6 edges (d0=64), N=1e5 nodes, d1=128.
// out = segsum(relu(BN(concat(h1[src],m)@W0^T + b0)), dst)  [N,128]
// Split: x[e] = A[src[e]] + B[e],  A = h1@Wa^T + b0 (N rows), B = m@Wb^T (E rows)
// R4 (resubmit; prior round was an infra failure): sorted-order edge GEMM.
// k1 4-deep unrolled (MLP). K3 gathers rows via perm and writes xbf in
// dst-sorted order -> K5 is a coalesced sequential stream.

typedef __attribute__((ext_vector_type(8))) short bf16x8;
typedef __attribute__((ext_vector_type(4))) float f32x4;

__device__ inline uint16_t f2bf(float x) {
    uint32_t u = __float_as_uint(x);
    return (uint16_t)((u + 0x7fffu + ((u >> 16) & 1u)) >> 16);  // RNE
}
__device__ inline float bf2f(uint32_t lo16) { return __uint_as_float(lo16 << 16); }

// ---------------- sort: histogram ----------------
__global__ __launch_bounds__(256) void k_hist(const int* __restrict__ dst,
                                              int* __restrict__ cnt, int E)
{
    int e = blockIdx.x * 256 + threadIdx.x;
    if (e < E) atomicAdd(&cnt[dst[e]], 1);
}

// ---------------- scan A: per-block (1024 elems) sums ----------------
__global__ __launch_bounds__(256) void k_scanA(const int* __restrict__ cnt,
                                               int* __restrict__ bsum, int N)
{
    int t = threadIdx.x, b = blockIdx.x;
    int i4 = b * 256 + t;
    int4 v = make_int4(0, 0, 0, 0);
    if (i4 < (N >> 2)) v = ((const int4*)cnt)[i4];
    int s = v.x + v.y + v.z + v.w;
    #pragma unroll
    for (int o = 1; o < 64; o <<= 1) s += __shfl_xor(s, o, 64);
    __shared__ int ws[4];
    if ((t & 63) == 0) ws[t >> 6] = s;
    __syncthreads();
    if (t == 0) bsum[b] = ws[0] + ws[1] + ws[2] + ws[3];
}

// ---------------- scan B: exclusive scan of block sums (nb<=128) ----------------
__global__ __launch_bounds__(128) void k_scanB(int* __restrict__ bsum, int nb)
{
    int t = threadIdx.x;
    int v = (t < nb) ? bsum[t] : 0;
    int lane = t & 63, w = t >> 6;
    int x = v;
    #pragma unroll
    for (int o = 1; o < 64; o <<= 1) {
        int y = __shfl_up(x, o, 64);
        if (lane >= o) x += y;
    }
    __shared__ int wt[2];
    if (lane == 63) wt[w] = x;
    __syncthreads();
    if (w == 1) x += wt[0];
    if (t < nb) bsum[t] = x - v;   // exclusive
}

// ---------------- scan C: write off/cur ----------------
__global__ __launch_bounds__(256) void k_scanC(const int* __restrict__ cnt,
                                               const int* __restrict__ bsum,
                                               int* __restrict__ off,
                                               int* __restrict__ cur, int N)
{
    int t = threadIdx.x, b = blockIdx.x;
    int i4 = b * 256 + t;
    bool ok = (i4 < (N >> 2));
    int4 v = make_int4(0, 0, 0, 0);
    if (ok) v = ((const int4*)cnt)[i4];
    int s = v.x + v.y + v.z + v.w;
    int lane = t & 63, w = t >> 6;
    int x = s;
    #pragma unroll
    for (int o = 1; o < 64; o <<= 1) {
        int y = __shfl_up(x, o, 64);
        if (lane >= o) x += y;
    }
    __shared__ int wt[4];
    if (lane == 63) wt[w] = x;
    __syncthreads();
    int wbase = 0;
    for (int k = 0; k < w; k++) wbase += wt[k];
    int excl = bsum[b] + wbase + x - s;
    if (ok) {
        int4 o4;
        o4.x = excl; o4.y = excl + v.x; o4.z = o4.y + v.y; o4.w = o4.z + v.z;
        ((int4*)off)[i4] = o4;
        ((int4*)cur)[i4] = o4;
    }
}

// ---------------- sort: fill permutation ----------------
__global__ __launch_bounds__(256) void k_perm(const int* __restrict__ dst,
                                              int* __restrict__ cur,
                                              int* __restrict__ perm, int E)
{
    int e = blockIdx.x * 256 + threadIdx.x;
    if (e < E) {
        int pos = atomicAdd(&cur[dst[e]], 1);
        perm[pos] = e;
    }
}

// ---------------- K1: h1bf[n] = bf16(sum of m rows of n's edges) ----------------
// 4-deep unrolled gather (4 independent in-flight rows per wave) + srcsort side-write.
__global__ __launch_bounds__(256) void k1_gather_h1(
    const float* __restrict__ m, const int* __restrict__ perm,
    const int* __restrict__ off, const int* __restrict__ cur,
    const int* __restrict__ src,
    ushort* __restrict__ h1bf, int* __restrict__ srcsort, int N)
{
    const int lane = threadIdx.x & 63;
    const int n = blockIdx.x * 4 + (threadIdx.x >> 6);
    if (n >= N) return;
    const int s0 = off[n], s1 = cur[n];

    // srcsort[i] = src[perm[i]] for this node's segment (src is L2/L3-resident)
    for (int j = s0 + lane; j < s1; j += 64) srcsort[j] = src[perm[j]];

    float a0 = 0.f, a1 = 0.f, a2 = 0.f, a3 = 0.f;
    int i = s0;
    for (; i + 4 <= s1; i += 4) {
        int e0 = perm[i], e1 = perm[i + 1], e2 = perm[i + 2], e3 = perm[i + 3];
        a0 += m[(size_t)e0 * 64 + lane];
        a1 += m[(size_t)e1 * 64 + lane];
        a2 += m[(size_t)e2 * 64 + lane];
        a3 += m[(size_t)e3 * 64 + lane];
    }
    for (; i < s1; i++) a0 += m[(size_t)perm[i] * 64 + lane];
    h1bf[(size_t)n * 64 + lane] = f2bf((a0 + a1) + (a2 + a3));
}

// ---------------- K2/K3: MFMA GEMM [R,64]@[64,128] ----------------
// a-frag: A[m=lane&15][k=quad*8+j]
//   EDGE : row = sorted position; gather m[perm[row]] (f32 -> bf16)
//   !EDGE: row = node; h1bf read directly (bf16)
// b-frag: B[k=quad*8+j][n=lane&15]  -> W0[n][wcol+k], register-resident (16 frags)
// C/D   : col=lane&15, row=quad*4+reg   (m89-verified)
template<bool EDGE>
__global__ __launch_bounds__(256) void gemm_mfma(
    const void* __restrict__ Xv,        // EDGE: float* m [E,64]; else ushort* h1bf [Npad,64]
    const float* __restrict__ W0,       // [128,128] row-major
    int wcol,                           // 0 (Wa) or 64 (Wb)
    const float* __restrict__ bias,     // !EDGE: b0
    const float* __restrict__ A,        // EDGE: gather table [N,128]
    const int*   __restrict__ srcS,     // EDGE: src in sorted order
    const int*   __restrict__ perm,     // EDGE: sorted pos -> edge
    float* __restrict__ outA,           // !EDGE output
    ushort* __restrict__ xbf,           // EDGE output bf16 (sorted order)
    float* __restrict__ gstats,         // EDGE: [0..127]=sum, [128..255]=sumsq
    int R, int ntiles)
{
    const int t  = threadIdx.x;
    const int l  = t & 63;
    const int lm = l & 15;              // m/n index within 16
    const int q  = l >> 4;              // quad 0..3
    const int wv = t >> 6;              // wave 0..3

    // ---- register-resident B fragments (bf16) ----
    bf16x8 bfr[8][2];
    #pragma unroll
    for (int nt = 0; nt < 8; nt++)
        #pragma unroll
        for (int ks = 0; ks < 2; ks++) {
            const float* wp = W0 + (nt * 16 + lm) * 128 + wcol + ks * 32 + q * 8;
            bf16x8 bf;
            #pragma unroll
            for (int j = 0; j < 8; j++) ((ushort*)&bf)[j] = f2bf(wp[j]);
            bfr[nt][ks] = bf;
        }
    float bs[8];
    if (!EDGE) {
        #pragma unroll
        for (int nt = 0; nt < 8; nt++) bs[nt] = bias[nt * 16 + lm];
    }

    __shared__ float sst[256];
    float lsum[8], lsq[8];
    if (EDGE) {
        #pragma unroll
        for (int nt = 0; nt < 8; nt++) { lsum[nt] = 0.f; lsq[nt] = 0.f; }
        sst[t] = 0.f;
        __syncthreads();
    }

    for (int tile = blockIdx.x; tile < ntiles; tile += gridDim.x) {
        const int r0 = tile * 64 + wv * 16;      // this wave's 16 rows

        // ---- a-fragments ----
        bf16x8 af[2];
        if (EDGE) {
            const int pr = perm[r0 + lm];        // gather row from original edge order
            const float* xp = (const float*)Xv + (size_t)pr * 64 + q * 8;
            #pragma unroll
            for (int ks = 0; ks < 2; ks++) {
                float4 w0 = *(const float4*)(xp + ks * 32);
                float4 w1 = *(const float4*)(xp + ks * 32 + 4);
                bf16x8 bf;
                ((ushort*)&bf)[0] = f2bf(w0.x); ((ushort*)&bf)[1] = f2bf(w0.y);
                ((ushort*)&bf)[2] = f2bf(w0.z); ((ushort*)&bf)[3] = f2bf(w0.w);
                ((ushort*)&bf)[4] = f2bf(w1.x); ((ushort*)&bf)[5] = f2bf(w1.y);
                ((ushort*)&bf)[6] = f2bf(w1.z); ((ushort*)&bf)[7] = f2bf(w1.w);
                af[ks] = bf;
            }
        } else {
            const ushort* xp = (const ushort*)Xv + (size_t)(r0 + lm) * 64 + q * 8;
            af[0] = *(const bf16x8*)xp;
            af[1] = *(const bf16x8*)(xp + 32);
        }

        f32x4 acc[8];
        #pragma unroll
        for (int nt = 0; nt < 8; nt++) acc[nt] = (f32x4){0.f, 0.f, 0.f, 0.f};
        #pragma unroll
        for (int ks = 0; ks < 2; ks++)
            #pragma unroll
            for (int nt = 0; nt < 8; nt++)
                acc[nt] = __builtin_amdgcn_mfma_f32_16x16x32_bf16(
                              af[ks], bfr[nt][ks], acc[nt], 0, 0, 0);

        if (!EDGE) {
            #pragma unroll
            for (int r = 0; r < 4; r++) {
                int row = r0 + q * 4 + r;
                if (row < R) {
                    #pragma unroll
                    for (int nt = 0; nt < 8; nt++)
                        outA[(size_t)row * 128 + nt * 16 + lm] = acc[nt][r] + bs[nt];
                }
            }
        } else {
            int4 rA = *(const int4*)(srcS + r0 + q * 4);   // src for rows q*4..q*4+3
            const int* rAp = &rA.x;
            #pragma unroll
            for (int r = 0; r < 4; r++) {
                int row = r0 + q * 4 + r;
                const float* Ar = A + (size_t)rAp[r] * 128;
                ushort* xo = xbf + (size_t)row * 128 + lm;
                #pragma unroll
                for (int nt = 0; nt < 8; nt++) {
                    float y = acc[nt][r] + Ar[nt * 16 + lm];
                    lsum[nt] += y;
                    lsq[nt]  += y * y;
                    xo[nt * 16] = f2bf(y);
                }
            }
        }
    }

    if (EDGE) {
        // reduce stats across quads (lanes with same lm), then block LDS, then global
        #pragma unroll
        for (int nt = 0; nt < 8; nt++) {
            #pragma unroll
            for (int o = 16; o < 64; o <<= 1) {
                lsum[nt] += __shfl_xor(lsum[nt], o, 64);
                lsq[nt]  += __shfl_xor(lsq[nt],  o, 64);
            }
        }
        __syncthreads();
        if (l < 16) {
            #pragma unroll
            for (int nt = 0; nt < 8; nt++) {
                atomicAdd(&sst[nt * 16 + l],       lsum[nt]);
                atomicAdd(&sst[128 + nt * 16 + l], lsq[nt]);
            }
        }
        __syncthreads();
        atomicAdd(&gstats[t], sst[t]);
    }
}

// ---------------- K4: finalize BN scale/shift ----------------
__global__ void k4_finalize(const float* __restrict__ gstats,
                            const float* __restrict__ g0,
                            const float* __restrict__ beta0,
                            float* __restrict__ sc, float Einv)
{
    int j = threadIdx.x;   // 128 threads
    float mu  = gstats[j] * Einv;
    float var = gstats[128 + j] * Einv - mu * mu;
    float s   = g0[j] * rsqrtf(var + 1e-5f);
    sc[j]       = s;
    sc[128 + j] = beta0[j] - mu * s;
}

// ---------------- K5: out[n] = sum relu(x*scale+shift) over n's edges ----------------
// xbf is dst-sorted: node n's rows are off[n]..cur[n], read fully coalesced.
__global__ __launch_bounds__(256) void k5_gather_out(
    const ushort* __restrict__ xbf,
    const int* __restrict__ off, const int* __restrict__ cur,
    const float* __restrict__ sc, float* __restrict__ out, int N)
{
    const int lane = threadIdx.x & 63;
    const int n = blockIdx.x * 4 + (threadIdx.x >> 6);
    if (n >= N) return;
    float2 s = ((const float2*)sc)[lane];
    float2 b = ((const float2*)(sc + 128))[lane];
    const int s0 = off[n], s1 = cur[n];
    float a0 = 0.f, a1 = 0.f, b0 = 0.f, b1 = 0.f;
    float c0 = 0.f, c1 = 0.f, d0 = 0.f, d1 = 0.f;
    int i = s0;
    for (; i + 4 <= s1; i += 4) {
        uint32_t p0 = *(const uint32_t*)(xbf + (size_t)i * 128 + 2 * lane);
        uint32_t p1 = *(const uint32_t*)(xbf + (size_t)(i + 1) * 128 + 2 * lane);
        uint32_t p2 = *(const uint32_t*)(xbf + (size_t)(i + 2) * 128 + 2 * lane);
        uint32_t p3 = *(const uint32_t*)(xbf + (size_t)(i + 3) * 128 + 2 * lane);
        a0 += fmaxf(bf2f(p0 & 0xffffu) * s.x + b.x, 0.f);
        a1 += fmaxf(bf2f(p0 >> 16)     * s.y + b.y, 0.f);
        b0 += fmaxf(bf2f(p1 & 0xffffu) * s.x + b.x, 0.f);
        b1 += fmaxf(bf2f(p1 >> 16)     * s.y + b.y, 0.f);
        c0 += fmaxf(bf2f(p2 & 0xffffu) * s.x + b.x, 0.f);
        c1 += fmaxf(bf2f(p2 >> 16)     * s.y + b.y, 0.f);
        d0 += fmaxf(bf2f(p3 & 0xffffu) * s.x + b.x, 0.f);
        d1 += fmaxf(bf2f(p3 >> 16)     * s.y + b.y, 0.f);
    }
    for (; i < s1; i++) {
        uint32_t p = *(const uint32_t*)(xbf + (size_t)i * 128 + 2 * lane);
        a0 += fmaxf(bf2f(p & 0xffffu) * s.x + b.x, 0.f);
        a1 += fmaxf(bf2f(p >> 16)     * s.y + b.y, 0.f);
    }
    ((float2*)(out + (size_t)n * 128))[lane] =
        make_float2((a0 + b0) + (c0 + d0), (a1 + b1) + (c1 + d1));
}

extern "C" void kernel_launch(void* const* d_in, const int* in_sizes, int n_in,
                              void* d_out, int out_size, void* d_ws, size_t ws_size,
                              hipStream_t stream)
{
    const float* m     = (const float*)d_in[0];
    const float* W0    = (const float*)d_in[1];
    const float* b0    = (const float*)d_in[2];
    const float* g0    = (const float*)d_in[3];
    const float* beta0 = (const float*)d_in[4];
    const int*   src   = (const int*)d_in[9];
    const int*   dst   = (const int*)d_in[10];
    float* out = (float*)d_out;

    const int E = in_sizes[0] / 64;     // 1,000,000
    const int N = out_size / 128;       // 100,000
    const int ntA = (N + 63) / 64;      // 1563 tiles for A-GEMM
    const int Npad = ntA * 64;          // padded row count for h1bf
    const int ntE = E / 64;             // 15625 tiles
    const int nb  = (N + 1023) / 1024;  // scan blocks

    auto align = [](size_t x) { return (x + 255) & ~(size_t)255; };
    char* ws = (char*)d_ws;
    size_t o_h1  = 0;
    size_t o_A   = align(o_h1 + (size_t)Npad * 64 * 2);
    size_t o_x   = align(o_A  + (size_t)N * 128 * 4);
    size_t o_gs  = align(o_x  + (size_t)E * 128 * 2);
    size_t o_sc  = align(o_gs + 256 * 4);
    size_t o_cnt = align(o_sc + 256 * 4);
    size_t o_off = align(o_cnt + (size_t)N * 4);
    size_t o_cur = align(o_off + (size_t)N * 4);
    size_t o_pm  = align(o_cur + (size_t)N * 4);
    size_t o_bs  = align(o_pm  + (size_t)E * 4);
    size_t o_ss  = align(o_bs  + 1024 * 4);
    ushort*   h1bf = (ushort*)(ws + o_h1);
    float*    A    = (float*)(ws + o_A);
    ushort*   xbf  = (ushort*)(ws + o_x);
    float*    gs   = (float*)(ws + o_gs);
    float*    sc   = (float*)(ws + o_sc);
    int*      cnt  = (int*)(ws + o_cnt);
    int*      off  = (int*)(ws + o_off);
    int*      cur  = (int*)(ws + o_cur);
    int*      perm = (int*)(ws + o_pm);
    int*      bsum = (int*)(ws + o_bs);
    int*      srcs = (int*)(ws + o_ss);   // src in sorted order

    hipMemsetAsync(cnt, 0, (size_t)N * 4, stream);
    hipMemsetAsync(gs, 0, 256 * 4, stream);

    // ---- counting sort by dst ----
    k_hist<<<(E + 255) / 256, 256, 0, stream>>>(dst, cnt, E);
    k_scanA<<<nb, 256, 0, stream>>>(cnt, bsum, N);
    k_scanB<<<1, 128, 0, stream>>>(bsum, nb);
    k_scanC<<<nb, 256, 0, stream>>>(cnt, bsum, off, cur, N);
    k_perm<<<(E + 255) / 256, 256, 0, stream>>>(dst, cur, perm, E);
    // after k_perm: cur[n] == segment end for node n

    // K1: h1bf = bf16(segsum(m, dst)) via 4-unrolled gather; also srcsort
    k1_gather_h1<<<(N + 3) / 4, 256, 0, stream>>>(m, perm, off, cur, src,
                                                  h1bf, srcs, N);

    // K2: A = h1 @ Wa^T + b0   (MFMA)
    gemm_mfma<false><<<ntA, 256, 0, stream>>>(h1bf, W0, 0, b0, nullptr, nullptr,
                                              nullptr, A, nullptr, nullptr, N, ntA);

    // K3: x[sorted i] = m[perm[i]] @ Wb^T + A[srcsort[i]]; stats; store bf16
    gemm_mfma<true><<<2048, 256, 0, stream>>>(m, W0, 64, nullptr, A, srcs, perm,
                                              nullptr, xbf, gs, E, ntE);

    // K4: scale/shift
    k4_finalize<<<1, 128, 0, stream>>>(gs, g0, beta0, sc, 1.0f / (float)E);

    // K5: out = segsum(relu(x*scale+shift), dst), fully coalesced stream
    k5_gather_out<<<(N + 3) / 4, 256, 0, stream>>>(xbf, off, cur, sc, out, N);
}

// Round 3
// 797.868 us; speedup vs baseline: 1.2258x; 1.0329x over previous
//
#include <hip/hip_runtime.h>
#include <hip/hip_bf16.h>
#include <stdint.h>

// E=1e6 edges (d0=64), N=1e5 nodes, d1=128.
// out = segsum(relu(BN(concat(h0[src],m)@W0^T + b0)), dst)  [N,128]
// Split: x[e] = A[src[e]] + B[e],  A = h0@Wa^T + b0 (N rows), B = m@Wb^T (E rows)
// R5: msort pass. k_scatter writes bf16(m) into dst-sorted order (scatter WRITES,
// non-stalling). K1 and K3 then stream msort sequentially; K3's only random
// access left is the L3-resident A-row gather; xbf written sequentially.

typedef __attribute__((ext_vector_type(8))) short bf16x8;
typedef __attribute__((ext_vector_type(4))) float f32x4;

__device__ inline uint16_t f2bf(float x) {
    uint32_t u = __float_as_uint(x);
    return (uint16_t)((u + 0x7fffu + ((u >> 16) & 1u)) >> 16);  // RNE
}
__device__ inline float bf2f(uint32_t lo16) { return __uint_as_float(lo16 << 16); }

// ---------------- sort: histogram ----------------
__global__ __launch_bounds__(256) void k_hist(const int* __restrict__ dst,
                                              int* __restrict__ cnt, int E)
{
    int e = blockIdx.x * 256 + threadIdx.x;
    if (e < E) atomicAdd(&cnt[dst[e]], 1);
}

// ---------------- scan A: per-block (1024 elems) sums ----------------
__global__ __launch_bounds__(256) void k_scanA(const int* __restrict__ cnt,
                                               int* __restrict__ bsum, int N)
{
    int t = threadIdx.x, b = blockIdx.x;
    int i4 = b * 256 + t;
    int4 v = make_int4(0, 0, 0, 0);
    if (i4 < (N >> 2)) v = ((const int4*)cnt)[i4];
    int s = v.x + v.y + v.z + v.w;
    #pragma unroll
    for (int o = 1; o < 64; o <<= 1) s += __shfl_xor(s, o, 64);
    __shared__ int ws[4];
    if ((t & 63) == 0) ws[t >> 6] = s;
    __syncthreads();
    if (t == 0) bsum[b] = ws[0] + ws[1] + ws[2] + ws[3];
}

// ---------------- scan B: exclusive scan of block sums (nb<=128) ----------------
__global__ __launch_bounds__(128) void k_scanB(int* __restrict__ bsum, int nb)
{
    int t = threadIdx.x;
    int v = (t < nb) ? bsum[t] : 0;
    int lane = t & 63, w = t >> 6;
    int x = v;
    #pragma unroll
    for (int o = 1; o < 64; o <<= 1) {
        int y = __shfl_up(x, o, 64);
        if (lane >= o) x += y;
    }
    __shared__ int wt[2];
    if (lane == 63) wt[w] = x;
    __syncthreads();
    if (w == 1) x += wt[0];
    if (t < nb) bsum[t] = x - v;   // exclusive
}

// ---------------- scan C: write off/cur ----------------
__global__ __launch_bounds__(256) void k_scanC(const int* __restrict__ cnt,
                                               const int* __restrict__ bsum,
                                               int* __restrict__ off,
                                               int* __restrict__ cur, int N)
{
    int t = threadIdx.x, b = blockIdx.x;
    int i4 = b * 256 + t;
    bool ok = (i4 < (N >> 2));
    int4 v = make_int4(0, 0, 0, 0);
    if (ok) v = ((const int4*)cnt)[i4];
    int s = v.x + v.y + v.z + v.w;
    int lane = t & 63, w = t >> 6;
    int x = s;
    #pragma unroll
    for (int o = 1; o < 64; o <<= 1) {
        int y = __shfl_up(x, o, 64);
        if (lane >= o) x += y;
    }
    __shared__ int wt[4];
    if (lane == 63) wt[w] = x;
    __syncthreads();
    int wbase = 0;
    for (int k = 0; k < w; k++) wbase += wt[k];
    int excl = bsum[b] + wbase + x - s;
    if (ok) {
        int4 o4;
        o4.x = excl; o4.y = excl + v.x; o4.z = o4.y + v.y; o4.w = o4.z + v.z;
        ((int4*)off)[i4] = o4;
        ((int4*)cur)[i4] = o4;
    }
}

// ---------------- sort: positions + srcS ----------------
__global__ __launch_bounds__(256) void k_perm(const int* __restrict__ dst,
                                              const int* __restrict__ src,
                                              int* __restrict__ cur,
                                              int* __restrict__ ipos,
                                              int* __restrict__ srcS, int E)
{
    int e = blockIdx.x * 256 + threadIdx.x;
    if (e < E) {
        int pos = atomicAdd(&cur[dst[e]], 1);
        ipos[e] = pos;            // sequential write
        srcS[pos] = src[e];       // scattered 4B write (non-stalling)
    }
}

// ---------------- scatter: msort[ipos[e]] = bf16(m[e]) ----------------
// Reads m fully coalesced; writes whole 128B bf16 rows to scattered positions.
__global__ __launch_bounds__(256) void k_scatter(const float* __restrict__ m,
                                                 const int* __restrict__ ipos,
                                                 ushort* __restrict__ msort, int E)
{
    int t = threadIdx.x;
    int e = blockIdx.x * 16 + (t >> 4);
    int l16 = t & 15;
    if (e >= E) return;
    int p = ipos[e];
    float4 v = *(const float4*)(m + (size_t)e * 64 + l16 * 4);
    ushort4 b;
    b.x = f2bf(v.x); b.y = f2bf(v.y); b.z = f2bf(v.z); b.w = f2bf(v.w);
    *(ushort4*)(msort + (size_t)p * 64 + l16 * 4) = b;
}

// ---------------- K1: h0bf[n] = bf16(sum of msort rows of n's segment) --------
// Fully sequential streaming read; 4-deep unrolled.
__global__ __launch_bounds__(256) void k1_gather_h1(
    const ushort* __restrict__ msort,
    const int* __restrict__ off, const int* __restrict__ cur,
    ushort* __restrict__ h1bf, int N)
{
    const int lane = threadIdx.x & 63;
    const int n = blockIdx.x * 4 + (threadIdx.x >> 6);
    if (n >= N) return;
    const int s0 = off[n], s1 = cur[n];
    float a0 = 0.f, a1 = 0.f, a2 = 0.f, a3 = 0.f;
    int i = s0;
    for (; i + 4 <= s1; i += 4) {
        a0 += bf2f(msort[(size_t)i * 64 + lane]);
        a1 += bf2f(msort[(size_t)(i + 1) * 64 + lane]);
        a2 += bf2f(msort[(size_t)(i + 2) * 64 + lane]);
        a3 += bf2f(msort[(size_t)(i + 3) * 64 + lane]);
    }
    for (; i < s1; i++) a0 += bf2f(msort[(size_t)i * 64 + lane]);
    h1bf[(size_t)n * 64 + lane] = f2bf((a0 + a1) + (a2 + a3));
}

// ---------------- K2/K3: MFMA GEMM [R,64]@[64,128] ----------------
// a-frag: bf16 rows read sequentially (msort for EDGE, h1bf for !EDGE)
// b-frag: B[k=quad*8+j][n=lane&15]  -> W0[n][wcol+k], register-resident (16 frags)
// C/D   : col=lane&15, row=quad*4+reg   (m89-verified)
template<bool EDGE>
__global__ __launch_bounds__(256) void gemm_mfma(
    const ushort* __restrict__ Xv,      // EDGE: msort [E,64]; else h1bf [Npad,64]
    const float* __restrict__ W0,       // [128,128] row-major
    int wcol,                           // 0 (Wa) or 64 (Wb)
    const float* __restrict__ bias,     // !EDGE: b0
    const float* __restrict__ A,        // EDGE: gather table [N,128]
    const int*   __restrict__ srcS,     // EDGE: src in sorted order
    float* __restrict__ outA,           // !EDGE output
    ushort* __restrict__ xbf,           // EDGE output bf16 (sorted order)
    float* __restrict__ gstats,         // EDGE: [0..127]=sum, [128..255]=sumsq
    int R, int ntiles)
{
    const int t  = threadIdx.x;
    const int l  = t & 63;
    const int lm = l & 15;              // m/n index within 16
    const int q  = l >> 4;              // quad 0..3
    const int wv = t >> 6;              // wave 0..3

    // ---- register-resident B fragments (bf16) ----
    bf16x8 bfr[8][2];
    #pragma unroll
    for (int nt = 0; nt < 8; nt++)
        #pragma unroll
        for (int ks = 0; ks < 2; ks++) {
            const float* wp = W0 + (nt * 16 + lm) * 128 + wcol + ks * 32 + q * 8;
            bf16x8 bf;
            #pragma unroll
            for (int j = 0; j < 8; j++) ((ushort*)&bf)[j] = f2bf(wp[j]);
            bfr[nt][ks] = bf;
        }
    float bs[8];
    if (!EDGE) {
        #pragma unroll
        for (int nt = 0; nt < 8; nt++) bs[nt] = bias[nt * 16 + lm];
    }

    __shared__ float sst[256];
    float lsum[8], lsq[8];
    if (EDGE) {
        #pragma unroll
        for (int nt = 0; nt < 8; nt++) { lsum[nt] = 0.f; lsq[nt] = 0.f; }
        sst[t] = 0.f;
        __syncthreads();
    }

    for (int tile = blockIdx.x; tile < ntiles; tile += gridDim.x) {
        const int r0 = tile * 64 + wv * 16;      // this wave's 16 rows

        // ---- a-fragments: sequential bf16 rows ----
        const ushort* xp = Xv + (size_t)(r0 + lm) * 64 + q * 8;
        bf16x8 af0 = *(const bf16x8*)xp;
        bf16x8 af1 = *(const bf16x8*)(xp + 32);

        f32x4 acc[8];
        #pragma unroll
        for (int nt = 0; nt < 8; nt++) acc[nt] = (f32x4){0.f, 0.f, 0.f, 0.f};
        #pragma unroll
        for (int nt = 0; nt < 8; nt++)
            acc[nt] = __builtin_amdgcn_mfma_f32_16x16x32_bf16(
                          af0, bfr[nt][0], acc[nt], 0, 0, 0);
        #pragma unroll
        for (int nt = 0; nt < 8; nt++)
            acc[nt] = __builtin_amdgcn_mfma_f32_16x16x32_bf16(
                          af1, bfr[nt][1], acc[nt], 0, 0, 0);

        if (!EDGE) {
            #pragma unroll
            for (int r = 0; r < 4; r++) {
                int row = r0 + q * 4 + r;
                if (row < R) {
                    #pragma unroll
                    for (int nt = 0; nt < 8; nt++)
                        outA[(size_t)row * 128 + nt * 16 + lm] = acc[nt][r] + bs[nt];
                }
            }
        } else {
            int4 rA = *(const int4*)(srcS + r0 + q * 4);   // src for rows q*4..q*4+3
            const int* rAp = &rA.x;
            #pragma unroll
            for (int r = 0; r < 4; r++) {
                int row = r0 + q * 4 + r;
                const float* Ar = A + (size_t)rAp[r] * 128;
                ushort* xo = xbf + (size_t)row * 128 + lm;
                #pragma unroll
                for (int nt = 0; nt < 8; nt++) {
                    float y = acc[nt][r] + Ar[nt * 16 + lm];
                    lsum[nt] += y;
                    lsq[nt]  += y * y;
                    xo[nt * 16] = f2bf(y);
                }
            }
        }
    }

    if (EDGE) {
        // reduce stats across quads (lanes with same lm), then block LDS, then global
        #pragma unroll
        for (int nt = 0; nt < 8; nt++) {
            #pragma unroll
            for (int o = 16; o < 64; o <<= 1) {
                lsum[nt] += __shfl_xor(lsum[nt], o, 64);
                lsq[nt]  += __shfl_xor(lsq[nt],  o, 64);
            }
        }
        __syncthreads();
        if (l < 16) {
            #pragma unroll
            for (int nt = 0; nt < 8; nt++) {
                atomicAdd(&sst[nt * 16 + l],       lsum[nt]);
                atomicAdd(&sst[128 + nt * 16 + l], lsq[nt]);
            }
        }
        __syncthreads();
        atomicAdd(&gstats[t], sst[t]);
    }
}

// ---------------- K4: finalize BN scale/shift ----------------
__global__ void k4_finalize(const float* __restrict__ gstats,
                            const float* __restrict__ g0,
                            const float* __restrict__ beta0,
                            float* __restrict__ sc, float Einv)
{
    int j = threadIdx.x;   // 128 threads
    float mu  = gstats[j] * Einv;
    float var = gstats[128 + j] * Einv - mu * mu;
    float s   = g0[j] * rsqrtf(var + 1e-5f);
    sc[j]       = s;
    sc[128 + j] = beta0[j] - mu * s;
}

// ---------------- K5: out[n] = sum relu(x*scale+shift) over n's edges ----------------
// xbf is dst-sorted: node n's rows are off[n]..cur[n], read fully coalesced.
__global__ __launch_bounds__(256) void k5_gather_out(
    const ushort* __restrict__ xbf,
    const int* __restrict__ off, const int* __restrict__ cur,
    const float* __restrict__ sc, float* __restrict__ out, int N)
{
    const int lane = threadIdx.x & 63;
    const int n = blockIdx.x * 4 + (threadIdx.x >> 6);
    if (n >= N) return;
    float2 s = ((const float2*)sc)[lane];
    float2 b = ((const float2*)(sc + 128))[lane];
    const int s0 = off[n], s1 = cur[n];
    float a0 = 0.f, a1 = 0.f, b0 = 0.f, b1 = 0.f;
    float c0 = 0.f, c1 = 0.f, d0 = 0.f, d1 = 0.f;
    int i = s0;
    for (; i + 4 <= s1; i += 4) {
        uint32_t p0 = *(const uint32_t*)(xbf + (size_t)i * 128 + 2 * lane);
        uint32_t p1 = *(const uint32_t*)(xbf + (size_t)(i + 1) * 128 + 2 * lane);
        uint32_t p2 = *(const uint32_t*)(xbf + (size_t)(i + 2) * 128 + 2 * lane);
        uint32_t p3 = *(const uint32_t*)(xbf + (size_t)(i + 3) * 128 + 2 * lane);
        a0 += fmaxf(bf2f(p0 & 0xffffu) * s.x + b.x, 0.f);
        a1 += fmaxf(bf2f(p0 >> 16)     * s.y + b.y, 0.f);
        b0 += fmaxf(bf2f(p1 & 0xffffu) * s.x + b.x, 0.f);
        b1 += fmaxf(bf2f(p1 >> 16)     * s.y + b.y, 0.f);
        c0 += fmaxf(bf2f(p2 & 0xffffu) * s.x + b.x, 0.f);
        c1 += fmaxf(bf2f(p2 >> 16)     * s.y + b.y, 0.f);
        d0 += fmaxf(bf2f(p3 & 0xffffu) * s.x + b.x, 0.f);
        d1 += fmaxf(bf2f(p3 >> 16)     * s.y + b.y, 0.f);
    }
    for (; i < s1; i++) {
        uint32_t p = *(const uint32_t*)(xbf + (size_t)i * 128 + 2 * lane);
        a0 += fmaxf(bf2f(p & 0xffffu) * s.x + b.x, 0.f);
        a1 += fmaxf(bf2f(p >> 16)     * s.y + b.y, 0.f);
    }
    ((float2*)(out + (size_t)n * 128))[lane] =
        make_float2((a0 + b0) + (c0 + d0), (a1 + b1) + (c1 + d1));
}

extern "C" void kernel_launch(void* const* d_in, const int* in_sizes, int n_in,
                              void* d_out, int out_size, void* d_ws, size_t ws_size,
                              hipStream_t stream)
{
    const float* m     = (const float*)d_in[0];
    const float* W0    = (const float*)d_in[1];
    const float* b0    = (const float*)d_in[2];
    const float* g0    = (const float*)d_in[3];
    const float* beta0 = (const float*)d_in[4];
    const int*   src   = (const int*)d_in[9];
    const int*   dst   = (const int*)d_in[10];
    float* out = (float*)d_out;

    const int E = in_sizes[0] / 64;     // 1,000,000
    const int N = out_size / 128;       // 100,000
    const int ntA = (N + 63) / 64;      // 1563 tiles for A-GEMM
    const int Npad = ntA * 64;          // padded row count for h1bf
    const int ntE = E / 64;             // 15625 tiles
    const int nb  = (N + 1023) / 1024;  // scan blocks

    auto align = [](size_t x) { return (x + 255) & ~(size_t)255; };
    char* ws = (char*)d_ws;
    size_t o_h1  = 0;
    size_t o_A   = align(o_h1 + (size_t)Npad * 64 * 2);
    size_t o_x   = align(o_A  + (size_t)N * 128 * 4);
    size_t o_gs  = align(o_x  + (size_t)E * 128 * 2);
    size_t o_sc  = align(o_gs + 256 * 4);
    size_t o_cnt = align(o_sc + 256 * 4);
    size_t o_off = align(o_cnt + (size_t)N * 4);
    size_t o_cur = align(o_off + (size_t)N * 4);
    size_t o_ip  = align(o_cur + (size_t)N * 4);
    size_t o_bs  = align(o_ip  + (size_t)E * 4);
    size_t o_ss  = align(o_bs  + 1024 * 4);
    size_t o_ms  = align(o_ss  + (size_t)E * 4);
    ushort*   h1bf  = (ushort*)(ws + o_h1);
    float*    A     = (float*)(ws + o_A);
    ushort*   xbf   = (ushort*)(ws + o_x);
    float*    gs    = (float*)(ws + o_gs);
    float*    sc    = (float*)(ws + o_sc);
    int*      cnt   = (int*)(ws + o_cnt);
    int*      off   = (int*)(ws + o_off);
    int*      cur   = (int*)(ws + o_cur);
    int*      ipos  = (int*)(ws + o_ip);
    int*      bsum  = (int*)(ws + o_bs);
    int*      srcs  = (int*)(ws + o_ss);   // src in sorted order
    ushort*   msort = (ushort*)(ws + o_ms);// bf16 m in sorted order

    hipMemsetAsync(cnt, 0, (size_t)N * 4, stream);
    hipMemsetAsync(gs, 0, 256 * 4, stream);

    // ---- counting sort by dst ----
    k_hist<<<(E + 255) / 256, 256, 0, stream>>>(dst, cnt, E);
    k_scanA<<<nb, 256, 0, stream>>>(cnt, bsum, N);
    k_scanB<<<1, 128, 0, stream>>>(bsum, nb);
    k_scanC<<<nb, 256, 0, stream>>>(cnt, bsum, off, cur, N);
    k_perm<<<(E + 255) / 256, 256, 0, stream>>>(dst, src, cur, ipos, srcs, E);
    // after k_perm: cur[n] == segment end for node n

    // scatter: msort = bf16(m) in dst-sorted order
    k_scatter<<<(E + 15) / 16, 256, 0, stream>>>(m, ipos, msort, E);

    // K1: h0bf = bf16(segsum(msort)) — sequential stream
    k1_gather_h1<<<(N + 3) / 4, 256, 0, stream>>>(msort, off, cur, h1bf, N);

    // K2: A = h0 @ Wa^T + b0   (MFMA)
    gemm_mfma<false><<<ntA, 256, 0, stream>>>(h1bf, W0, 0, b0, nullptr, nullptr,
                                              A, nullptr, nullptr, N, ntA);

    // K3: x[i] = msort[i] @ Wb^T + A[srcS[i]]; stats; store bf16 (all sequential
    //     except the L3-resident A gather)
    gemm_mfma<true><<<2048, 256, 0, stream>>>(msort, W0, 64, nullptr, A, srcs,
                                              nullptr, xbf, gs, E, ntE);

    // K4: scale/shift
    k4_finalize<<<1, 128, 0, stream>>>(gs, g0, beta0, sc, 1.0f / (float)E);

    // K5: out = segsum(relu(x*scale+shift), dst), fully coalesced stream
    k5_gather_out<<<(N + 3) / 4, 256, 0, stream>>>(xbf, off, cur, sc, out, N);
}